// Round 1
// baseline (4187.400 us; speedup 1.0000x reference)
//
#include <hip/hip_runtime.h>
#include <math.h>

#define B_   2
#define S_   2048
#define H_   1024
#define NH_  16
#define NKV_ 4
#define HD_  64
#define R_   (NH_ / NKV_)   // 4 q-heads per kv-head

// ---------------------------------------------------------------------------
// Generic fp32 GEMM: C[M,N] = A[M,K] @ W[K,N], all row-major contiguous.
// 64x64 block tile, BK=16, 256 threads, 4x4 micro-tile per thread.
// ---------------------------------------------------------------------------
__global__ __launch_bounds__(256) void gemm_f32(const float* __restrict__ A,
                                                const float* __restrict__ W,
                                                float* __restrict__ C,
                                                int M, int N, int K) {
    __shared__ float As[16][68];   // As[k][m], padded: 68*4B=272B rows keep 16B align
    __shared__ float Bs[16][68];   // Bs[k][n]

    const int tid  = threadIdx.x;
    const int row0 = blockIdx.y * 64;
    const int col0 = blockIdx.x * 64;
    const int tr   = tid >> 4;          // 0..15
    const int tc   = tid & 15;          // 0..15

    // A staging: thread loads A[row0 + tid/4][k0 + (tid%4)*4 .. +3]
    const int ar = tid >> 2;            // 0..63
    const int ac = (tid & 3) << 2;      // 0,4,8,12
    // B staging: thread loads W[k0 + tid/16][col0 + (tid%16)*4 .. +3]
    const int br = tid >> 4;            // 0..15
    const int bc = (tid & 15) << 2;     // 0..60

    float acc[4][4] = {};

    for (int k0 = 0; k0 < K; k0 += 16) {
        float4 av = *(const float4*)(A + (size_t)(row0 + ar) * K + k0 + ac);
        float4 wv = *(const float4*)(W + (size_t)(k0 + br) * N + col0 + bc);
        As[ac + 0][ar] = av.x;
        As[ac + 1][ar] = av.y;
        As[ac + 2][ar] = av.z;
        As[ac + 3][ar] = av.w;
        *(float4*)&Bs[br][bc] = wv;
        __syncthreads();

#pragma unroll
        for (int kk = 0; kk < 16; kk++) {
            float4 a4 = *(const float4*)&As[kk][tr * 4];
            float4 b4 = *(const float4*)&Bs[kk][tc * 4];
            acc[0][0] += a4.x * b4.x; acc[0][1] += a4.x * b4.y;
            acc[0][2] += a4.x * b4.z; acc[0][3] += a4.x * b4.w;
            acc[1][0] += a4.y * b4.x; acc[1][1] += a4.y * b4.y;
            acc[1][2] += a4.y * b4.z; acc[1][3] += a4.y * b4.w;
            acc[2][0] += a4.z * b4.x; acc[2][1] += a4.z * b4.y;
            acc[2][2] += a4.z * b4.z; acc[2][3] += a4.z * b4.w;
            acc[3][0] += a4.w * b4.x; acc[3][1] += a4.w * b4.y;
            acc[3][2] += a4.w * b4.z; acc[3][3] += a4.w * b4.w;
        }
        __syncthreads();
    }

#pragma unroll
    for (int i = 0; i < 4; i++) {
        float4 ov = { acc[i][0], acc[i][1], acc[i][2], acc[i][3] };
        *(float4*)(C + (size_t)(row0 + tr * 4 + i) * N + col0 + tc * 4) = ov;
    }
}

// ---------------------------------------------------------------------------
// RoPE (in-place on q and k). One thread per (token, head, d<32) pair:
//   out[d]    = x[d]*cos[d]     - x[d+32]*sin[d]
//   out[d+32] = x[d+32]*cos[d+32] + x[d]*sin[d+32]
// ---------------------------------------------------------------------------
__global__ __launch_bounds__(256) void rope_kernel(float* __restrict__ qb,
                                                   float* __restrict__ kb,
                                                   const float* __restrict__ cosb,
                                                   const float* __restrict__ sinb) {
    const int half = HD_ / 2;  // 32
    int idx = blockIdx.x * blockDim.x + threadIdx.x;
    // total = B*S*(NH+NKV)*32 — launched exactly
    int token = idx / ((NH_ + NKV_) * half);
    int rem   = idx % ((NH_ + NKV_) * half);
    int head  = rem / half;
    int d     = rem % half;
    int spos  = token % S_;

    float c0 = cosb[spos * HD_ + d];
    float c1 = cosb[spos * HD_ + d + half];
    float s0 = sinb[spos * HD_ + d];
    float s1 = sinb[spos * HD_ + d + half];

    float* p;
    if (head < NH_) p = qb + ((size_t)token * NH_ + head) * HD_;
    else            p = kb + ((size_t)token * NKV_ + (head - NH_)) * HD_;

    float x0 = p[d];
    float x1 = p[d + half];
    p[d]        = x0 * c0 - x1 * s0;
    p[d + half] = x1 * c1 + x0 * s1;
}

// ---------------------------------------------------------------------------
// Flash-style causal GQA attention.
// grid = (S/16, B*NH); block = 256 threads.
// Thread (r = tid>>4, c = tid&15): query row q0+r, output cols c*4..c*4+3,
// score keys c*4..c*4+3 of the current 64-key tile.
// Online softmax state (m, l) replicated across the 16 threads of a row —
// all compute identical values from the same LDS data.
// ---------------------------------------------------------------------------
__global__ __launch_bounds__(256) void attn_kernel(const float* __restrict__ qb,
                                                   const float* __restrict__ kb,
                                                   const float* __restrict__ vb,
                                                   const float* __restrict__ maskb,
                                                   float* __restrict__ ab) {
    const int tid = threadIdx.x;
    const int bh  = blockIdx.y;
    const int b   = bh / NH_;
    const int h   = bh % NH_;
    const int g   = h / R_;
    const int q0  = blockIdx.x * 16;
    const int r   = tid >> 4;   // query row in tile
    const int c   = tid & 15;   // col group

    __shared__ float ks[64][HD_];     // 16 KB
    __shared__ float vs[64][HD_];     // 16 KB
    __shared__ float sc[16][65];      // padded to kill 4-way bank conflicts

    // Load this thread's q row into registers (16 float4 = 64 floats).
    float4 qreg[16];
    {
        const float* qp = qb + (((size_t)(b * S_ + q0 + r)) * NH_ + h) * HD_;
#pragma unroll
        for (int i = 0; i < 16; i++) qreg[i] = ((const float4*)qp)[i];
    }
    const int q_abs = q0 + r;

    float m = -1e30f, l = 0.0f;
    float4 o = {0.f, 0.f, 0.f, 0.f};

    const int ktiles = (q0 + 15) / 64 + 1;
    for (int kt = 0; kt < ktiles; kt++) {
        const int base_key = kt * 64;

        // ---- stage K and V tiles (64 keys x 64 dims) ----
#pragma unroll
        for (int i = 0; i < 4; i++) {
            int flat = tid + i * 256;       // 0..1023 float4 slots
            int row  = flat >> 4;           // 0..63
            int col4 = flat & 15;           // 0..15
            size_t goff = (((size_t)(b * S_ + base_key + row)) * NKV_ + g) * HD_ + col4 * 4;
            *(float4*)&ks[row][col4 * 4] = *(const float4*)(kb + goff);
            *(float4*)&vs[row][col4 * 4] = *(const float4*)(vb + goff);
        }
        __syncthreads();

        // ---- scores: this thread computes keys j0..j0+3 for row r ----
        {
            const int j0 = c * 4;
            float sacc[4] = {0.f, 0.f, 0.f, 0.f};
#pragma unroll
            for (int dd = 0; dd < 16; dd++) {
                int d4 = (dd + c) & 15;     // rotate start to avoid bank conflicts
                float4 qv = qreg[d4];
#pragma unroll
                for (int jj = 0; jj < 4; jj++) {
                    float4 kv = *(const float4*)&ks[j0 + jj][d4 * 4];
                    sacc[jj] += qv.x * kv.x + qv.y * kv.y + qv.z * kv.z + qv.w * kv.w;
                }
            }
#pragma unroll
            for (int jj = 0; jj < 4; jj++) {
                int key = base_key + j0 + jj;
                float val;
                if (key <= q_abs)
                    val = sacc[jj] * 0.125f + (1.0f - maskb[b * S_ + key]) * -1e9f;
                else
                    val = -1e30f;
                sc[r][j0 + jj] = val;
            }
        }
        __syncthreads();

        // ---- online softmax + PV (all 16 threads of row r redundantly) ----
        {
            float rm = -1e30f;
#pragma unroll 8
            for (int j = 0; j < 64; j++) rm = fmaxf(rm, sc[r][j]);
            float nm    = fmaxf(m, rm);
            float alpha = __expf(m - nm);
            o.x *= alpha; o.y *= alpha; o.z *= alpha; o.w *= alpha;
            l *= alpha;
            float rs = 0.f;
#pragma unroll 4
            for (int j = 0; j < 64; j++) {
                float p = __expf(sc[r][j] - nm);
                rs += p;
                float4 vv = *(const float4*)&vs[j][c * 4];
                o.x += p * vv.x; o.y += p * vv.y; o.z += p * vv.z; o.w += p * vv.w;
            }
            l += rs;
            m = nm;
        }
        __syncthreads();   // all reads done before next tile's staging
    }

    // ---- write normalized output ----
    float inv = 1.0f / l;
    float4 ov = { o.x * inv, o.y * inv, o.z * inv, o.w * inv };
    *(float4*)(ab + (((size_t)(b * S_ + q0 + r)) * NH_ + h) * HD_ + c * 4) = ov;
}

// ---------------------------------------------------------------------------
extern "C" void kernel_launch(void* const* d_in, const int* in_sizes, int n_in,
                              void* d_out, int out_size, void* d_ws, size_t ws_size,
                              hipStream_t stream) {
    const float* x     = (const float*)d_in[0];
    const float* cosb  = (const float*)d_in[1];
    const float* sinb  = (const float*)d_in[2];
    const float* maskb = (const float*)d_in[3];
    const float* Wq    = (const float*)d_in[4];
    const float* Wk    = (const float*)d_in[5];
    const float* Wv    = (const float*)d_in[6];
    const float* Wo    = (const float*)d_in[7];

    // q lives in d_out (same size: B*S*NH*HD == B*S*H); it is fully consumed
    // by attn_kernel before the final GEMM overwrites d_out.
    float* qb  = (float*)d_out;
    float* kb  = (float*)d_ws;                              // 1M floats
    float* vb  = kb + (size_t)B_ * S_ * NKV_ * HD_;         // 1M floats
    float* ab  = vb + (size_t)B_ * S_ * NKV_ * HD_;         // 4M floats
    float* out = (float*)d_out;

    const int M = B_ * S_;
    dim3 blk(256);

    gemm_f32<<<dim3((NH_ * HD_) / 64, M / 64), blk, 0, stream>>>(x, Wq, qb, M, NH_ * HD_, H_);
    gemm_f32<<<dim3((NKV_ * HD_) / 64, M / 64), blk, 0, stream>>>(x, Wk, kb, M, NKV_ * HD_, H_);
    gemm_f32<<<dim3((NKV_ * HD_) / 64, M / 64), blk, 0, stream>>>(x, Wv, vb, M, NKV_ * HD_, H_);

    const int nrope = B_ * S_ * (NH_ + NKV_) * (HD_ / 2);
    rope_kernel<<<dim3(nrope / 256), blk, 0, stream>>>(qb, kb, cosb, sinb);

    attn_kernel<<<dim3(S_ / 16, B_ * NH_), blk, 0, stream>>>(qb, kb, vb, maskb, ab);

    gemm_f32<<<dim3(H_ / 64, M / 64), blk, 0, stream>>>(ab, Wo, out, M, H_, H_);
}

// Round 2
// 1380.936 us; speedup vs baseline: 3.0323x; 3.0323x over previous
//
#include <hip/hip_runtime.h>
#include <math.h>

#define B_   2
#define S_   2048
#define H_   1024
#define NH_  16
#define NKV_ 4
#define HD_  64
#define R_   (NH_ / NKV_)   // 4 q-heads per kv-head

// ---------------------------------------------------------------------------
// Generic fp32 GEMM: C[M,N] = A[M,K] @ W[K,N], all row-major contiguous.
// 64x64 block tile, BK=16, 256 threads, 4x4 micro-tile per thread.
// ---------------------------------------------------------------------------
__global__ __launch_bounds__(256) void gemm_f32(const float* __restrict__ A,
                                                const float* __restrict__ W,
                                                float* __restrict__ C,
                                                int M, int N, int K) {
    __shared__ float As[16][68];
    __shared__ float Bs[16][68];

    const int tid  = threadIdx.x;
    const int row0 = blockIdx.y * 64;
    const int col0 = blockIdx.x * 64;
    const int tr   = tid >> 4;
    const int tc   = tid & 15;

    const int ar = tid >> 2;
    const int ac = (tid & 3) << 2;
    const int br = tid >> 4;
    const int bc = (tid & 15) << 2;

    float acc[4][4] = {};

    for (int k0 = 0; k0 < K; k0 += 16) {
        float4 av = *(const float4*)(A + (size_t)(row0 + ar) * K + k0 + ac);
        float4 wv = *(const float4*)(W + (size_t)(k0 + br) * N + col0 + bc);
        As[ac + 0][ar] = av.x;
        As[ac + 1][ar] = av.y;
        As[ac + 2][ar] = av.z;
        As[ac + 3][ar] = av.w;
        *(float4*)&Bs[br][bc] = wv;
        __syncthreads();

#pragma unroll
        for (int kk = 0; kk < 16; kk++) {
            float4 a4 = *(const float4*)&As[kk][tr * 4];
            float4 b4 = *(const float4*)&Bs[kk][tc * 4];
            acc[0][0] += a4.x * b4.x; acc[0][1] += a4.x * b4.y;
            acc[0][2] += a4.x * b4.z; acc[0][3] += a4.x * b4.w;
            acc[1][0] += a4.y * b4.x; acc[1][1] += a4.y * b4.y;
            acc[1][2] += a4.y * b4.z; acc[1][3] += a4.y * b4.w;
            acc[2][0] += a4.z * b4.x; acc[2][1] += a4.z * b4.y;
            acc[2][2] += a4.z * b4.z; acc[2][3] += a4.z * b4.w;
            acc[3][0] += a4.w * b4.x; acc[3][1] += a4.w * b4.y;
            acc[3][2] += a4.w * b4.z; acc[3][3] += a4.w * b4.w;
        }
        __syncthreads();
    }

#pragma unroll
    for (int i = 0; i < 4; i++) {
        float4 ov = { acc[i][0], acc[i][1], acc[i][2], acc[i][3] };
        *(float4*)(C + (size_t)(row0 + tr * 4 + i) * N + col0 + tc * 4) = ov;
    }
}

// ---------------------------------------------------------------------------
// RoPE (in-place on q and k).
// ---------------------------------------------------------------------------
__global__ __launch_bounds__(256) void rope_kernel(float* __restrict__ qb,
                                                   float* __restrict__ kb,
                                                   const float* __restrict__ cosb,
                                                   const float* __restrict__ sinb) {
    const int half = HD_ / 2;  // 32
    int idx = blockIdx.x * blockDim.x + threadIdx.x;
    int token = idx / ((NH_ + NKV_) * half);
    int rem   = idx % ((NH_ + NKV_) * half);
    int head  = rem / half;
    int d     = rem % half;
    int spos  = token % S_;

    float c0 = cosb[spos * HD_ + d];
    float c1 = cosb[spos * HD_ + d + half];
    float s0 = sinb[spos * HD_ + d];
    float s1 = sinb[spos * HD_ + d + half];

    float* p;
    if (head < NH_) p = qb + ((size_t)token * NH_ + head) * HD_;
    else            p = kb + ((size_t)token * NKV_ + (head - NH_)) * HD_;

    float x0 = p[d];
    float x1 = p[d + half];
    p[d]        = x0 * c0 - x1 * s0;
    p[d + half] = x1 * c1 + x0 * s1;
}

// ---------------------------------------------------------------------------
// Flash-style causal GQA attention, v2.
// grid = (S/128, B*NH); block = 256 threads.
// Thread (row = tid>>1, hf = tid&1) owns query row q0+row's half-dims
// [hf*32, hf*32+32): q-half and o-half live in registers. Per key:
// partial dot over 32 dims, __shfl_xor(1) combines halves, exp, PV-half.
// No redundant softmax work, no score LDS round-trip.
// Scores buffered 16/chunk in regs so running-max rescale is amortized.
// ---------------------------------------------------------------------------
__global__ __launch_bounds__(256) void attn_kernel(const float* __restrict__ qb,
                                                   const float* __restrict__ kb,
                                                   const float* __restrict__ vb,
                                                   const float* __restrict__ maskb,
                                                   float* __restrict__ ab) {
    const int tid = threadIdx.x;
    const int bh  = blockIdx.y;
    const int b   = bh / NH_;
    const int h   = bh % NH_;
    const int g   = h / R_;
    const int q0  = blockIdx.x * 128;
    const int row = tid >> 1;      // 0..127
    const int hf  = tid & 1;       // which 32-dim half
    const int q_abs = q0 + row;

    __shared__ float ks[64][HD_];  // 16 KB
    __shared__ float vs[64][HD_];  // 16 KB
    __shared__ float msk[64];

    // q half in registers (8 float4 = 32 floats)
    float4 q[8];
    {
        const float* qp = qb + (((size_t)(b * S_ + q_abs)) * NH_ + h) * HD_ + hf * 32;
#pragma unroll
        for (int i = 0; i < 8; i++) q[i] = ((const float4*)qp)[i];
    }

    float4 o[8] = {};
    float m = -1e30f, l = 0.0f;

    const int ktiles = 2 * blockIdx.x + 2;   // keys up to q0+127 inclusive
    for (int kt = 0; kt < ktiles; kt++) {
        const int base_key = kt * 64;

        // ---- stage K and V tiles (64 keys x 64 dims) + mask ----
#pragma unroll
        for (int i = 0; i < 4; i++) {
            int flat = tid + i * 256;       // 0..1023 float4 slots
            int krow = flat >> 4;           // 0..63
            int col4 = flat & 15;           // 0..15
            size_t goff = (((size_t)(b * S_ + base_key + krow)) * NKV_ + g) * HD_ + col4 * 4;
            *(float4*)&ks[krow][col4 * 4] = *(const float4*)(kb + goff);
            *(float4*)&vs[krow][col4 * 4] = *(const float4*)(vb + goff);
        }
        if (tid < 64) msk[tid] = maskb[b * S_ + base_key + tid];
        __syncthreads();

        // ---- process tile in 16-key chunks ----
#pragma unroll
        for (int j0 = 0; j0 < 64; j0 += 16) {
            float sc[16];
#pragma unroll
            for (int jj = 0; jj < 16; jj++) {
                const int j = j0 + jj;
                const float4* kp = (const float4*)&ks[j][hf * 32];
                float4 a = {0.f, 0.f, 0.f, 0.f};
#pragma unroll
                for (int i = 0; i < 8; i++) {
                    float4 kv = kp[i];
                    a.x += q[i].x * kv.x; a.y += q[i].y * kv.y;
                    a.z += q[i].z * kv.z; a.w += q[i].w * kv.w;
                }
                float part = (a.x + a.y) + (a.z + a.w);
                float full = part + __shfl_xor(part, 1);
                const int key = base_key + j;
                float val = full * 0.125f + (1.0f - msk[j]) * -1e9f;
                sc[jj] = (key <= q_abs) ? val : -1e30f;
            }
            // chunk max → merge into running (m, l, o)
            float cmax = sc[0];
#pragma unroll
            for (int jj = 1; jj < 16; jj++) cmax = fmaxf(cmax, sc[jj]);
            float nm    = fmaxf(m, cmax);
            float alpha = __expf(m - nm);
#pragma unroll
            for (int i = 0; i < 8; i++) {
                o[i].x *= alpha; o[i].y *= alpha;
                o[i].z *= alpha; o[i].w *= alpha;
            }
            l *= alpha;
            m = nm;
#pragma unroll
            for (int jj = 0; jj < 16; jj++) {
                float p = __expf(sc[jj] - nm);
                l += p;
                const float4* vp = (const float4*)&vs[j0 + jj][hf * 32];
#pragma unroll
                for (int i = 0; i < 8; i++) {
                    float4 vv = vp[i];
                    o[i].x += p * vv.x; o[i].y += p * vv.y;
                    o[i].z += p * vv.z; o[i].w += p * vv.w;
                }
            }
        }
        __syncthreads();   // reads done before next tile's staging
    }

    // ---- write normalized output half ----
    float inv = 1.0f / l;
    float* op = ab + (((size_t)(b * S_ + q_abs)) * NH_ + h) * HD_ + hf * 32;
#pragma unroll
    for (int i = 0; i < 8; i++) {
        float4 ov = { o[i].x * inv, o[i].y * inv, o[i].z * inv, o[i].w * inv };
        ((float4*)op)[i] = ov;
    }
}

// ---------------------------------------------------------------------------
extern "C" void kernel_launch(void* const* d_in, const int* in_sizes, int n_in,
                              void* d_out, int out_size, void* d_ws, size_t ws_size,
                              hipStream_t stream) {
    const float* x     = (const float*)d_in[0];
    const float* cosb  = (const float*)d_in[1];
    const float* sinb  = (const float*)d_in[2];
    const float* maskb = (const float*)d_in[3];
    const float* Wq    = (const float*)d_in[4];
    const float* Wk    = (const float*)d_in[5];
    const float* Wv    = (const float*)d_in[6];
    const float* Wo    = (const float*)d_in[7];

    float* qb  = (float*)d_out;                             // consumed before final GEMM
    float* kb  = (float*)d_ws;                              // 1M floats
    float* vb  = kb + (size_t)B_ * S_ * NKV_ * HD_;         // 1M floats
    float* ab  = vb + (size_t)B_ * S_ * NKV_ * HD_;         // 4M floats
    float* out = (float*)d_out;

    const int M = B_ * S_;
    dim3 blk(256);

    gemm_f32<<<dim3((NH_ * HD_) / 64, M / 64), blk, 0, stream>>>(x, Wq, qb, M, NH_ * HD_, H_);
    gemm_f32<<<dim3((NKV_ * HD_) / 64, M / 64), blk, 0, stream>>>(x, Wk, kb, M, NKV_ * HD_, H_);
    gemm_f32<<<dim3((NKV_ * HD_) / 64, M / 64), blk, 0, stream>>>(x, Wv, vb, M, NKV_ * HD_, H_);

    const int nrope = B_ * S_ * (NH_ + NKV_) * (HD_ / 2);
    rope_kernel<<<dim3(nrope / 256), blk, 0, stream>>>(qb, kb, cosb, sinb);

    attn_kernel<<<dim3(S_ / 128, B_ * NH_), blk, 0, stream>>>(qb, kb, vb, maskb, ab);

    gemm_f32<<<dim3(H_ / 64, M / 64), blk, 0, stream>>>(ab, Wo, out, M, H_, H_);
}